// Round 15
// baseline (482.693 us; speedup 1.0000x reference)
//
#include <hip/hip_runtime.h>

typedef __bf16 bf16x8 __attribute__((ext_vector_type(8)));
typedef float f32x4 __attribute__((ext_vector_type(4)));
typedef float f32x16 __attribute__((ext_vector_type(16)));
typedef unsigned short u16x8 __attribute__((ext_vector_type(8)));

#define SM_SCALE 0.180336880111120419f  /* 0.125 * log2(e) */

__device__ __forceinline__ unsigned short f2bf(float f) {
  unsigned int u = __float_as_uint(f);
  u += 0x7fff + ((u >> 16) & 1);   // round-to-nearest-even
  return (unsigned short)(u >> 16);
}

// -------- LayerNorm (z-merged pair): fp32 in -> bf16 normalized out -------
__global__ __launch_bounds__(256) void ln_kernel(
    const float* __restrict__ x1, const float* __restrict__ x2,
    const float* __restrict__ g1, const float* __restrict__ b1,
    const float* __restrict__ g2, const float* __restrict__ b2,
    unsigned short* __restrict__ o1, unsigned short* __restrict__ o2) {
  int z = blockIdx.y;
  const float* x = z ? x2 : x1;
  const float* g = z ? g2 : g1;
  const float* b = z ? b2 : b1;
  unsigned short* out = z ? o2 : o1;
  int row = blockIdx.x;
  int tid = threadIdx.x;
  const float4 v = ((const float4*)(x + (size_t)row * 1024))[tid];
  float s1 = v.x + v.y + v.z + v.w;
  float s2 = v.x * v.x + v.y * v.y + v.z * v.z + v.w * v.w;
  for (int o = 32; o >= 1; o >>= 1) { s1 += __shfl_xor(s1, o); s2 += __shfl_xor(s2, o); }
  __shared__ float red[2][4];
  int wid = tid >> 6, lane = tid & 63;
  if (lane == 0) { red[0][wid] = s1; red[1][wid] = s2; }
  __syncthreads();
  s1 = red[0][0] + red[0][1] + red[0][2] + red[0][3];
  s2 = red[1][0] + red[1][1] + red[1][2] + red[1][3];
  float mu = s1 * (1.0f / 1024.0f);
  float var = s2 * (1.0f / 1024.0f) - mu * mu;
  float rstd = rsqrtf(var + 1e-5f);
  int c0 = tid * 4;
  ushort4 o;
  o.x = f2bf((v.x - mu) * rstd * g[c0 + 0] + b[c0 + 0]);
  o.y = f2bf((v.y - mu) * rstd * g[c0 + 1] + b[c0 + 1]);
  o.z = f2bf((v.z - mu) * rstd * g[c0 + 2] + b[c0 + 2]);
  o.w = f2bf((v.w - mu) * rstd * g[c0 + 3] + b[c0 + 3]);
  ((ushort4*)(out + (size_t)row * 1024))[tid] = o;
}

// -- Weight transpose + cast (z-merged pair): [K][Nn] f32 -> [Nn][K] bf16 --
__global__ __launch_bounds__(256) void transpose_w(
    const float* __restrict__ in0, const float* __restrict__ in1,
    unsigned short* __restrict__ out0, unsigned short* __restrict__ out1,
    int K, int Nn) {
  __shared__ float t[32][33];
  const float* in = blockIdx.z ? in1 : in0;
  unsigned short* out = blockIdx.z ? out1 : out0;
  int tid = threadIdx.x;
  int tx = tid & 31, ty = tid >> 5;
  int n0 = blockIdx.x * 32, k0 = blockIdx.y * 32;
#pragma unroll
  for (int i = 0; i < 4; i++) {
    int r = ty + i * 8;
    t[r][tx] = in[(size_t)(k0 + r) * Nn + n0 + tx];
  }
  __syncthreads();
#pragma unroll
  for (int i = 0; i < 4; i++) {
    int r = ty + i * 8;
    out[(size_t)(n0 + r) * K + k0 + tx] = f2bf(t[tx][r]);
  }
}

// ---- 256x256 8-wave bf16 GEMM, z-merged pair with XCD-half partition -----
__global__ __launch_bounds__(512, 2) void gemm256(
    const unsigned short* __restrict__ A0, const unsigned short* __restrict__ A1,
    const unsigned short* __restrict__ BT0, const unsigned short* __restrict__ BT1,
    int M, int N, int K, int mode,
    unsigned short* __restrict__ ob0, unsigned short* __restrict__ ob1,
    const float* __restrict__ bias0, const float* __restrict__ bias1,
    float* __restrict__ of0, float* __restrict__ of1) {
  __shared__ char lds[131072];
  const int tid = threadIdx.x;
  const int lane = tid & 63, wid = tid >> 6;
  const int wm = wid >> 2, wn = wid & 3;
  int gx = gridDim.x, gy = gridDim.y;
  int hb = ((int)blockIdx.z * gy + (int)blockIdx.y) * gx + (int)blockIdx.x;
  int c = hb & 7, j = hb >> 3;
  int z = c >> 2;
  int chunk = gy >> 2;
  int by = (c & 3) * chunk + (j % chunk);
  int bx = j / chunk;
  int bm = by * 256, bn = bx * 256;
  const unsigned short* A = z ? A1 : A0;
  const unsigned short* BT = z ? BT1 : BT0;
  const int NT = K >> 6;
  const size_t K2 = (size_t)K * 2;

  int p0 = tid * 16, p1 = 8192 + tid * 16;
  int r0 = p0 >> 7, r1 = p1 >> 7;
  int c0 = (p0 & 127) ^ ((r0 & 7) << 4);
  int c1 = (p1 & 127) ^ ((r1 & 7) << 4);
  const char* sA0 = (const char*)A + (size_t)(bm + r0) * K2 + c0;
  const char* sA0b = (const char*)A + (size_t)(bm + r1) * K2 + c1;
  const char* sA1 = (const char*)A + (size_t)(bm + 128 + r0) * K2 + c0;
  const char* sA1b = (const char*)A + (size_t)(bm + 128 + r1) * K2 + c1;
  const char* sB0 = (const char*)BT + (size_t)(bn + r0) * K2 + c0;
  const char* sB0b = (const char*)BT + (size_t)(bn + r1) * K2 + c1;
  const char* sB1 = (const char*)BT + (size_t)(bn + 128 + r0) * K2 + c0;
  const char* sB1b = (const char*)BT + (size_t)(bn + 128 + r1) * K2 + c1;

#define GL(src, dst)                                                        \
  __builtin_amdgcn_global_load_lds(                                         \
      (__attribute__((address_space(1))) void*)(src),                       \
      (__attribute__((address_space(3))) void*)(dst), 16, 0, 0)
#define STAGE_TILE(base, t)                                                 \
  {                                                                         \
    size_t ko = (size_t)(t) * 128;                                          \
    GL(sA0 + ko, (base) + p0);  GL(sA0b + ko, (base) + p1);                 \
    GL(sA1 + ko, (base) + 16384 + p0);  GL(sA1b + ko, (base) + 16384 + p1); \
    GL(sB0 + ko, (base) + 32768 + p0);  GL(sB0b + ko, (base) + 32768 + p1); \
    GL(sB1 + ko, (base) + 49152 + p0);  GL(sB1b + ko, (base) + 49152 + p1); \
  }

  int l15 = lane & 15, l4 = lane >> 4;
  int sx = (l15 & 7) << 4;
  int aoff0 = wm * 16384 + l15 * 128 + ((l4 * 16) ^ sx);
  int aoff1 = wm * 16384 + l15 * 128 + ((64 + l4 * 16) ^ sx);
  int brl = (wn & 1) * 64 + l15;
  int boff0 = 32768 + (wn >> 1) * 16384 + brl * 128 + ((l4 * 16) ^ sx);
  int boff1 = 32768 + (wn >> 1) * 16384 + brl * 128 + ((64 + l4 * 16) ^ sx);

  f32x4 acc[8][4] = {};

  STAGE_TILE(lds, 0);
  STAGE_TILE(lds + 65536, 1);
  asm volatile("s_waitcnt vmcnt(8)" ::: "memory");
  __builtin_amdgcn_sched_barrier(0);
  __builtin_amdgcn_s_barrier();
  __builtin_amdgcn_sched_barrier(0);

  for (int t = 0; t < NT; ++t) {
    char* buf = lds + (t & 1) * 65536;
    const char* a0 = buf + aoff0;
    const char* a1 = buf + aoff1;
    const char* b0 = buf + boff0;
    const char* b1 = buf + boff1;
    bf16x8 afA[4][2], afB[4][2], bfr[4][2];
#pragma unroll
    for (int ni = 0; ni < 4; ni++) {
      bfr[ni][0] = *(const bf16x8*)(b0 + ni * 2048);
      bfr[ni][1] = *(const bf16x8*)(b1 + ni * 2048);
    }
#pragma unroll
    for (int mi = 0; mi < 4; mi++) {
      afA[mi][0] = *(const bf16x8*)(a0 + mi * 2048);
      afA[mi][1] = *(const bf16x8*)(a1 + mi * 2048);
    }
#pragma unroll
    for (int mi = 0; mi < 4; mi++) {
      afB[mi][0] = *(const bf16x8*)(a0 + 8192 + mi * 2048);
      afB[mi][1] = *(const bf16x8*)(a1 + 8192 + mi * 2048);
    }
    __builtin_amdgcn_s_setprio(1);
#pragma unroll
    for (int mi = 0; mi < 4; mi++)
#pragma unroll
      for (int ni = 0; ni < 4; ni++) {
        acc[mi][ni] = __builtin_amdgcn_mfma_f32_16x16x32_bf16(afA[mi][0], bfr[ni][0], acc[mi][ni], 0, 0, 0);
        acc[mi][ni] = __builtin_amdgcn_mfma_f32_16x16x32_bf16(afA[mi][1], bfr[ni][1], acc[mi][ni], 0, 0, 0);
      }
    __builtin_amdgcn_s_setprio(0);
    asm volatile("s_waitcnt lgkmcnt(0)" ::: "memory");
    __builtin_amdgcn_sched_barrier(0);
    __builtin_amdgcn_s_barrier();
    __builtin_amdgcn_sched_barrier(0);
    if (t + 2 < NT) STAGE_TILE(buf, t + 2);
    __builtin_amdgcn_s_setprio(1);
#pragma unroll
    for (int mi = 0; mi < 4; mi++)
#pragma unroll
      for (int ni = 0; ni < 4; ni++) {
        acc[mi + 4][ni] = __builtin_amdgcn_mfma_f32_16x16x32_bf16(afB[mi][0], bfr[ni][0], acc[mi + 4][ni], 0, 0, 0);
        acc[mi + 4][ni] = __builtin_amdgcn_mfma_f32_16x16x32_bf16(afB[mi][1], bfr[ni][1], acc[mi + 4][ni], 0, 0, 0);
      }
    __builtin_amdgcn_s_setprio(0);
    if (t + 2 < NT) {
      asm volatile("s_waitcnt vmcnt(8)" ::: "memory");
    } else {
      asm volatile("s_waitcnt vmcnt(0)" ::: "memory");
    }
    __builtin_amdgcn_sched_barrier(0);
    __builtin_amdgcn_s_barrier();
    __builtin_amdgcn_sched_barrier(0);
  }

  if (mode == 0) {
    unsigned short* ob = z ? ob1 : ob0;
#pragma unroll
    for (int mi = 0; mi < 8; mi++)
#pragma unroll
      for (int ni = 0; ni < 4; ni++) {
        int col = bn + wn * 64 + ni * 16 + l15;
#pragma unroll
        for (int r = 0; r < 4; r++) {
          int m = bm + wm * 128 + mi * 16 + l4 * 4 + r;
          ob[(size_t)m * N + col] = f2bf(acc[mi][ni][r]);
        }
      }
  } else {
    const float* bias = z ? bias1 : bias0;
    float* outf = z ? of1 : of0;
#pragma unroll
    for (int mi = 0; mi < 8; mi++)
#pragma unroll
      for (int ni = 0; ni < 4; ni++) {
        int col = bn + wn * 64 + ni * 16 + l15;
        float bv = bias[col];
#pragma unroll
        for (int r = 0; r < 4; r++) {
          int m = bm + wm * 128 + mi * 16 + l4 * 4 + r;
          outf[(size_t)m * N + col] = acc[mi][ni][r] + bv;
        }
      }
  }
#undef GL
#undef STAGE_TILE
}

// ---- Flash attention, cross-tile pipelined: QK(t+1) || PV(t) -------------
// Swapped-QK^T 32x32, fixed-shift softmax, XCD-colocated (R13),
// pa double-state (macro parity), 2xK + 2xV LDS dbuf, exact counted vmcnt.
__global__ __launch_bounds__(256, 3) void attn_kernel(
    const unsigned short* __restrict__ qkvA, const unsigned short* __restrict__ qkvB,
    unsigned short* __restrict__ oA, unsigned short* __restrict__ oB) {
  __shared__ char lds[32768];  // kb0 @0, kb1 @8K, vb0 @16K, vb1 @24K
  int tid = threadIdx.x, lane = tid & 63, wid = tid >> 6;
  int hi = lane >> 5, lq = lane & 31;
  int bid = ((int)blockIdx.z * (int)gridDim.y + (int)blockIdx.y) * (int)gridDim.x +
            (int)blockIdx.x;
  int c = bid & 7, j = bid >> 3;
  int qblk = j & 15, z = (j >> 4) & 1, unit = c * 8 + (j >> 5);
  const unsigned short* Qg = z ? qkvB : qkvA;
  const unsigned short* KVg = z ? qkvA : qkvB;
  unsigned short* O = z ? oB : oA;
  int b = unit >> 4, h = unit & 15;
  int qn = qblk * 128 + wid * 32;
  const unsigned short* Qb = Qg + ((size_t)(b * 2048 + qn + lq)) * 3072 + h * 64;
  const unsigned short* Kb = KVg + (size_t)(b * 2048) * 3072 + 1024 + h * 64;
  const unsigned short* Vb = KVg + (size_t)(b * 2048) * 3072 + 2048 + h * 64;

  bf16x8 qf[4];
#pragma unroll
  for (int cc = 0; cc < 4; cc++) {
    u16x8 qr = *(const u16x8*)(Qb + cc * 16 + hi * 8);
    union { unsigned short s[8]; bf16x8 v; } u;
#pragma unroll
    for (int jj = 0; jj < 8; jj++)
      u.s[jj] = f2bf(__uint_as_float((unsigned int)qr[jj] << 16) * SM_SCALE);
    qf[cc] = u.v;
  }

  f32x16 oacc[2] = {};          // O^T: [d-half][16 regs]; col q = lane&31
  float l_run = 0.f;            // lane-local; cross-half shfl at epilogue
  bf16x8 paA[4], paB[4];

  int vj = tid & 31, vd0 = (tid >> 5) * 8;
  u16x8 vA0, vA1, vB0, vB1;

  char* kb0 = lds;          char* kb1 = lds + 8192;
  char* vb0 = lds + 16384;  char* vb1 = lds + 24576;

#define SBAR __builtin_amdgcn_sched_barrier(0)
#define STAGE_K(kbuf, t)                                                                 \
  {                                                                                      \
    _Pragma("unroll") for (int i_ = 0; i_ < 2; i_++) {                                   \
      int off_ = tid * 16 + i_ * 4096;                                                   \
      int row_ = off_ >> 7;                                                              \
      int col_ = off_ & 127;                                                             \
      const char* src_ = (const char*)Kb + (size_t)((t) * 64 + row_) * 6144 +            \
                         (col_ ^ ((row_ & 7) << 4));                                     \
      __builtin_amdgcn_global_load_lds(                                                  \
          (__attribute__((address_space(1))) void*)src_,                                 \
          (__attribute__((address_space(3))) void*)((kbuf) + off_), 16, 0, 0);           \
    }                                                                                    \
  }
#define LOAD_V(t, R0, R1)                                                                \
  {                                                                                      \
    const unsigned short* vp_ = Vb + (size_t)((t) * 64 + 2 * vj) * 3072 + vd0;           \
    R0 = *(const u16x8*)vp_;                                                             \
    R1 = *(const u16x8*)(vp_ + 3072);                                                    \
  }
#define WRITE_V(vbuf, R0, R1)                                                            \
  {                                                                                      \
    _Pragma("unroll") for (int i_ = 0; i_ < 8; i_++) {                                   \
      unsigned int w_ = (unsigned int)R0[i_] | ((unsigned int)R1[i_] << 16);             \
      int d_ = vd0 + i_;                                                                 \
      int byte_ = (d_ * 128 + vj * 4) ^ ((d_ & 7) << 4);                                 \
      *(unsigned int*)((vbuf) + byte_) = w_;                                             \
    }                                                                                    \
  }
// QK for tile x from KBRD into st0/st1 (both kpos halves)
#define QK_BLOCK(KBRD)                                                                   \
  {                                                                                      \
    int rb_ = lq * 128 + hi * 16;                                                        \
    int sq_ = (lq & 7) << 4;                                                             \
    __builtin_amdgcn_s_setprio(1);                                                       \
    _Pragma("unroll") for (int cc = 0; cc < 4; cc++) {                                   \
      bf16x8 kf_ = *(const bf16x8*)((KBRD) + ((rb_ + cc * 32) ^ sq_));                   \
      st0 = __builtin_amdgcn_mfma_f32_32x32x16_bf16(kf_, qf[cc], st0, 0, 0, 0);          \
    }                                                                                    \
    _Pragma("unroll") for (int cc = 0; cc < 4; cc++) {                                   \
      bf16x8 kf_ = *(const bf16x8*)((KBRD) + ((4096 + rb_ + cc * 32) ^ sq_));            \
      st1 = __builtin_amdgcn_mfma_f32_32x32x16_bf16(kf_, qf[cc], st1, 0, 0, 0);          \
    }                                                                                    \
    __builtin_amdgcn_s_setprio(0);                                                       \
  }
// exp/pack st0,st1 -> PAN[0..3], accumulate l_run
#define SM_PACK(PAN)                                                                     \
  {                                                                                      \
    float rs_ = 0.f;                                                                     \
    _Pragma("unroll") for (int i = 0; i < 16; i++) { st0[i] = exp2f(st0[i]); rs_ += st0[i]; } \
    _Pragma("unroll") for (int i = 0; i < 16; i++) { st1[i] = exp2f(st1[i]); rs_ += st1[i]; } \
    l_run += rs_;                                                                        \
    _Pragma("unroll") for (int ksl = 0; ksl < 2; ksl++) {                                \
      unsigned int wA, wB, wC, wD;                                                       \
      asm("v_cvt_pk_bf16_f32 %0, %1, %2" : "=v"(wA) : "v"(st0[8 * ksl + 0]), "v"(st0[8 * ksl + 1])); \
      asm("v_cvt_pk_bf16_f32 %0, %1, %2" : "=v"(wC) : "v"(st0[8 * ksl + 2]), "v"(st0[8 * ksl + 3])); \
      asm("v_cvt_pk_bf16_f32 %0, %1, %2" : "=v"(wB) : "v"(st0[8 * ksl + 4]), "v"(st0[8 * ksl + 5])); \
      asm("v_cvt_pk_bf16_f32 %0, %1, %2" : "=v"(wD) : "v"(st0[8 * ksl + 6]), "v"(st0[8 * ksl + 7])); \
      asm("v_permlane32_swap_b32 %0, %1" : "+v"(wA), "+v"(wB));                          \
      asm("v_permlane32_swap_b32 %0, %1" : "+v"(wC), "+v"(wD));                          \
      union { unsigned int w[4]; bf16x8 v; } u_;                                         \
      u_.w[0] = wA; u_.w[1] = wC; u_.w[2] = wB; u_.w[3] = wD;                            \
      PAN[ksl] = u_.v;                                                                   \
    }                                                                                    \
    _Pragma("unroll") for (int ksl = 0; ksl < 2; ksl++) {                                \
      unsigned int wA, wB, wC, wD;                                                       \
      asm("v_cvt_pk_bf16_f32 %0, %1, %2" : "=v"(wA) : "v"(st1[8 * ksl + 0]), "v"(st1[8 * ksl + 1])); \
      asm("v_cvt_pk_bf16_f32 %0, %1, %2" : "=v"(wC) : "v"(st1[8 * ksl + 2]), "v"(st1[8 * ksl + 3])); \
      asm("v_cvt_pk_bf16_f32 %0, %1, %2" : "=v"(wB) : "v"(st1[8 * ksl + 4]), "v"(st1[8 * ksl + 5])); \
      asm("v_cvt_pk_bf16_f32 %0, %1, %2" : "=v"(wD) : "v"(st1[8 * ksl + 6]), "v"(st1[8 * ksl + 7])); \
      asm("v_permlane32_swap_b32 %0, %1" : "+v"(wA), "+v"(wB));                          \
      asm("v_permlane32_swap_b32 %0, %1" : "+v"(wC), "+v"(wD));                          \
      union { unsigned int w[4]; bf16x8 v; } u_;                                         \
      u_.w[0] = wA; u_.w[1] = wC; u_.w[2] = wB; u_.w[3] = wD;                            \
      PAN[2 + ksl] = u_.v;                                                               \
    }                                                                                    \
  }
// one pipeline iteration for tile T (PV(T) + QK(T+1))
#define ITER(T, KBST, KBRD, VBRD, VBWR, PAC, PAN, VL0, VL1, VW0, VW1)                    \
  {                                                                                      \
    if ((T) + 2 < 32) {                                                                  \
      STAGE_K(KBST, (T) + 2); SBAR;                                                      \
      LOAD_V((T) + 2, VL0, VL1); SBAR;                                                   \
    }                                                                                    \
    f32x16 st0 = {}, st1 = {};                                                           \
    if ((T) + 1 < 32) QK_BLOCK(KBRD);                                                    \
    /* PV(T) from VBRD using PAC */                                                      \
    __builtin_amdgcn_s_setprio(1);                                                       \
    _Pragma("unroll") for (int dh = 0; dh < 2; dh++) {                                   \
      int rb2_ = (dh * 32 + lq) * 128 + hi * 16;                                         \
      int sw2_ = (lq & 7) << 4;                                                          \
      _Pragma("unroll") for (int ks = 0; ks < 4; ks++) {                                 \
        bf16x8 vf_ = *(const bf16x8*)((VBRD) + ((rb2_ + ks * 32) ^ sw2_));               \
        oacc[dh] = __builtin_amdgcn_mfma_f32_32x32x16_bf16(vf_, PAC[ks], oacc[dh], 0, 0, 0); \
      }                                                                                  \
    }                                                                                    \
    __builtin_amdgcn_s_setprio(0);                                                       \
    if ((T) + 2 < 32) { asm volatile("s_waitcnt vmcnt(2)" ::: "memory"); }               \
    else if ((T) + 1 < 32) { asm volatile("s_waitcnt vmcnt(0)" ::: "memory"); }          \
    if ((T) + 1 < 32) WRITE_V(VBWR, VW0, VW1);                                           \
    if ((T) + 1 < 32) SM_PACK(PAN);                                                      \
    asm volatile("s_waitcnt lgkmcnt(0)" ::: "memory");                                   \
    SBAR; __builtin_amdgcn_s_barrier(); SBAR;                                            \
  }

  // ---- prologue: stage K0,K1; V0->LDS; V1 in regs; build pa(0) ----
  STAGE_K(kb0, 0); SBAR;
  LOAD_V(0, vA0, vA1); SBAR;
  STAGE_K(kb1, 1); SBAR;
  LOAD_V(1, vB0, vB1); SBAR;
  asm volatile("s_waitcnt vmcnt(2)" ::: "memory");   // K0,V0,K1 retired; V1 in flight
  WRITE_V(vb0, vA0, vA1);
  asm volatile("s_waitcnt lgkmcnt(0)" ::: "memory");
  SBAR; __builtin_amdgcn_s_barrier(); SBAR;
  {
    f32x16 st0 = {}, st1 = {};
    QK_BLOCK(kb0);
    SM_PACK(paA);
  }
  SBAR; __builtin_amdgcn_s_barrier(); SBAR;          // kb0 reads done before restage

  for (int t = 0; t < 32; t += 2) {
    ITER(t,     kb0, kb1, vb0, vb1, paA, paB, vA0, vA1, vB0, vB1);
    ITER(t + 1, kb1, kb0, vb1, vb0, paB, paA, vB0, vB1, vA0, vA1);
  }

  // epilogue: O^T regs -> LDS (swizzled) -> coalesced global stores
  l_run += __shfl_xor(l_run, 32);
  float inv = 1.0f / l_run;
  char* ol = lds + wid * 4096;
#pragma unroll
  for (int dh = 0; dh < 2; dh++)
#pragma unroll
    for (int i = 0; i < 8; i++) {
      float a0 = oacc[dh][2 * i] * inv, a1 = oacc[dh][2 * i + 1] * inv;
      unsigned int w;
      asm("v_cvt_pk_bf16_f32 %0, %1, %2" : "=v"(w) : "v"(a0), "v"(a1));
      int r2 = 2 * i;
      int d = dh * 32 + (r2 & 3) + 8 * (r2 >> 2) + 4 * hi;
      int byte = (lq * 128 + d * 2) ^ ((lq & 7) << 4);
      *(unsigned int*)(ol + byte) = w;
    }
  __syncthreads();
#pragma unroll
  for (int i2 = 0; i2 < 4; i2++) {
    int qr = i2 * 8 + (lane >> 3), s = lane & 7;
    int byte = (qr * 128 + s * 16) ^ ((qr & 7) << 4);
    uint4 w4 = *(const uint4*)(ol + byte);
    size_t row = (size_t)b * 2048 + qn + qr;
    *(uint4*)((char*)O + row * 2048 + h * 128 + s * 16) = w4;
  }
#undef SBAR
#undef STAGE_K
#undef LOAD_V
#undef WRITE_V
#undef QK_BLOCK
#undef SM_PACK
#undef ITER
}

extern "C" void kernel_launch(void* const* d_in, const int* in_sizes, int n_in,
                              void* d_out, int out_size, void* d_ws, size_t ws_size,
                              hipStream_t stream) {
  const float* x1 = (const float*)d_in[0];
  const float* x2 = (const float*)d_in[1];
  const float* ln1_g = (const float*)d_in[2];
  const float* ln1_b = (const float*)d_in[3];
  const float* ln2_g = (const float*)d_in[4];
  const float* ln2_b = (const float*)d_in[5];
  const float* w_qkv1 = (const float*)d_in[6];
  const float* w_qkv2 = (const float*)d_in[7];
  const float* w_out1 = (const float*)d_in[8];
  const float* b_out1 = (const float*)d_in[9];
  const float* w_out2 = (const float*)d_in[10];
  const float* b_out2 = (const float*)d_in[11];

  char* ws = (char*)d_ws;
  size_t off = 0;
  auto alloc = [&](size_t bytes) {
    char* p = ws + off;
    off += (bytes + 255) & ~(size_t)255;
    return p;
  };
  const size_t SZ16 = (size_t)8192 * 1024 * 2;   // 16.78 MB
  const size_t SZ48 = (size_t)8192 * 3072 * 2;   // 50.33 MB
  unsigned short* x1n = (unsigned short*)alloc(SZ16);
  unsigned short* x2n = (unsigned short*)alloc(SZ16);
  unsigned short* wq1T = (unsigned short*)alloc((size_t)3072 * 1024 * 2);
  unsigned short* wq2T = (unsigned short*)alloc((size_t)3072 * 1024 * 2);
  unsigned short* wo1T = (unsigned short*)alloc((size_t)1024 * 1024 * 2);
  unsigned short* wo2T = (unsigned short*)alloc((size_t)1024 * 1024 * 2);
  unsigned short* qkv1 = (unsigned short*)alloc(SZ48);
  unsigned short* qkv2 = (unsigned short*)alloc(SZ48);
  unsigned short* at1 = x1n;  // overlay: x1n dead after QKV gemm
  unsigned short* at2 = x2n;  // overlay: x2n dead after QKV gemm

  ln_kernel<<<dim3(8192, 2), dim3(256), 0, stream>>>(x1, x2, ln1_g, ln1_b,
                                                     ln2_g, ln2_b, x1n, x2n);
  transpose_w<<<dim3(96, 32, 2), dim3(256), 0, stream>>>(w_qkv1, w_qkv2, wq1T, wq2T,
                                                         1024, 3072);
  transpose_w<<<dim3(32, 32, 2), dim3(256), 0, stream>>>(w_out1, w_out2, wo1T, wo2T,
                                                         1024, 1024);
  gemm256<<<dim3(12, 32, 2), dim3(512), 0, stream>>>(
      x1n, x2n, wq1T, wq2T, 8192, 3072, 1024, 0,
      qkv1, qkv2, nullptr, nullptr, nullptr, nullptr);
  attn_kernel<<<dim3(16, 64, 2), dim3(256), 0, stream>>>(qkv1, qkv2, at1, at2);
  gemm256<<<dim3(4, 32, 2), dim3(512), 0, stream>>>(
      at1, at2, wo1T, wo2T, 8192, 1024, 1024, 1,
      nullptr, nullptr, b_out1, b_out2,
      (float*)d_out, (float*)d_out + (size_t)8192 * 1024);
}

// Round 16
// 369.017 us; speedup vs baseline: 1.3080x; 1.3080x over previous
//
#include <hip/hip_runtime.h>

typedef __bf16 bf16x8 __attribute__((ext_vector_type(8)));
typedef float f32x4 __attribute__((ext_vector_type(4)));
typedef float f32x16 __attribute__((ext_vector_type(16)));
typedef unsigned short u16x8 __attribute__((ext_vector_type(8)));

#define SM_SCALE 0.180336880111120419f  /* 0.125 * log2(e) */

__device__ __forceinline__ unsigned short f2bf(float f) {
  unsigned int u = __float_as_uint(f);
  u += 0x7fff + ((u >> 16) & 1);   // round-to-nearest-even
  return (unsigned short)(u >> 16);
}

// -------- LayerNorm (z-merged pair): fp32 in -> bf16 normalized out -------
__global__ __launch_bounds__(256) void ln_kernel(
    const float* __restrict__ x1, const float* __restrict__ x2,
    const float* __restrict__ g1, const float* __restrict__ b1,
    const float* __restrict__ g2, const float* __restrict__ b2,
    unsigned short* __restrict__ o1, unsigned short* __restrict__ o2) {
  int z = blockIdx.y;
  const float* x = z ? x2 : x1;
  const float* g = z ? g2 : g1;
  const float* b = z ? b2 : b1;
  unsigned short* out = z ? o2 : o1;
  int row = blockIdx.x;
  int tid = threadIdx.x;
  const float4 v = ((const float4*)(x + (size_t)row * 1024))[tid];
  float s1 = v.x + v.y + v.z + v.w;
  float s2 = v.x * v.x + v.y * v.y + v.z * v.z + v.w * v.w;
  for (int o = 32; o >= 1; o >>= 1) { s1 += __shfl_xor(s1, o); s2 += __shfl_xor(s2, o); }
  __shared__ float red[2][4];
  int wid = tid >> 6, lane = tid & 63;
  if (lane == 0) { red[0][wid] = s1; red[1][wid] = s2; }
  __syncthreads();
  s1 = red[0][0] + red[0][1] + red[0][2] + red[0][3];
  s2 = red[1][0] + red[1][1] + red[1][2] + red[1][3];
  float mu = s1 * (1.0f / 1024.0f);
  float var = s2 * (1.0f / 1024.0f) - mu * mu;
  float rstd = rsqrtf(var + 1e-5f);
  int c0 = tid * 4;
  ushort4 o;
  o.x = f2bf((v.x - mu) * rstd * g[c0 + 0] + b[c0 + 0]);
  o.y = f2bf((v.y - mu) * rstd * g[c0 + 1] + b[c0 + 1]);
  o.z = f2bf((v.z - mu) * rstd * g[c0 + 2] + b[c0 + 2]);
  o.w = f2bf((v.w - mu) * rstd * g[c0 + 3] + b[c0 + 3]);
  ((ushort4*)(out + (size_t)row * 1024))[tid] = o;
}

// -- Weight transpose + cast, all four weights in ONE launch ----------------
// bx < 96: qkv pair ([1024][3072] -> [3072][1024]); bx >= 96: out pair
// ([1024][1024] -> [1024][1024], only bx-96 < 32 active columns).
__global__ __launch_bounds__(256) void transpose_w(
    const float* __restrict__ q0, const float* __restrict__ q1,
    unsigned short* __restrict__ qo0, unsigned short* __restrict__ qo1,
    const float* __restrict__ w0, const float* __restrict__ w1,
    unsigned short* __restrict__ wo0, unsigned short* __restrict__ wo1) {
  __shared__ float t[32][33];
  int bx = blockIdx.x;
  const float* in;
  unsigned short* out;
  int Nn, n0;
  if (bx < 96) {
    in = blockIdx.z ? q1 : q0;
    out = blockIdx.z ? qo1 : qo0;
    Nn = 3072; n0 = bx * 32;
  } else {
    in = blockIdx.z ? w1 : w0;
    out = blockIdx.z ? wo1 : wo0;
    Nn = 1024; n0 = (bx - 96) * 32;
  }
  const int K = 1024;
  int tid = threadIdx.x;
  int tx = tid & 31, ty = tid >> 5;
  int k0 = blockIdx.y * 32;
#pragma unroll
  for (int i = 0; i < 4; i++) {
    int r = ty + i * 8;
    t[r][tx] = in[(size_t)(k0 + r) * Nn + n0 + tx];
  }
  __syncthreads();
#pragma unroll
  for (int i = 0; i < 4; i++) {
    int r = ty + i * 8;
    out[(size_t)(n0 + r) * K + k0 + tx] = f2bf(t[tx][r]);
  }
}

// ---- 256x256 8-wave bf16 GEMM, z-merged pair with XCD-half partition -----
__global__ __launch_bounds__(512, 2) void gemm256(
    const unsigned short* __restrict__ A0, const unsigned short* __restrict__ A1,
    const unsigned short* __restrict__ BT0, const unsigned short* __restrict__ BT1,
    int M, int N, int K, int mode,
    unsigned short* __restrict__ ob0, unsigned short* __restrict__ ob1,
    const float* __restrict__ bias0, const float* __restrict__ bias1,
    float* __restrict__ of0, float* __restrict__ of1) {
  __shared__ char lds[131072];
  const int tid = threadIdx.x;
  const int lane = tid & 63, wid = tid >> 6;
  const int wm = wid >> 2, wn = wid & 3;
  int gx = gridDim.x, gy = gridDim.y;
  int hb = ((int)blockIdx.z * gy + (int)blockIdx.y) * gx + (int)blockIdx.x;
  int c = hb & 7, j = hb >> 3;
  int z = c >> 2;
  int chunk = gy >> 2;
  int by = (c & 3) * chunk + (j % chunk);
  int bx = j / chunk;
  int bm = by * 256, bn = bx * 256;
  const unsigned short* A = z ? A1 : A0;
  const unsigned short* BT = z ? BT1 : BT0;
  const int NT = K >> 6;
  const size_t K2 = (size_t)K * 2;

  int p0 = tid * 16, p1 = 8192 + tid * 16;
  int r0 = p0 >> 7, r1 = p1 >> 7;
  int c0 = (p0 & 127) ^ ((r0 & 7) << 4);
  int c1 = (p1 & 127) ^ ((r1 & 7) << 4);
  const char* sA0 = (const char*)A + (size_t)(bm + r0) * K2 + c0;
  const char* sA0b = (const char*)A + (size_t)(bm + r1) * K2 + c1;
  const char* sA1 = (const char*)A + (size_t)(bm + 128 + r0) * K2 + c0;
  const char* sA1b = (const char*)A + (size_t)(bm + 128 + r1) * K2 + c1;
  const char* sB0 = (const char*)BT + (size_t)(bn + r0) * K2 + c0;
  const char* sB0b = (const char*)BT + (size_t)(bn + r1) * K2 + c1;
  const char* sB1 = (const char*)BT + (size_t)(bn + 128 + r0) * K2 + c0;
  const char* sB1b = (const char*)BT + (size_t)(bn + 128 + r1) * K2 + c1;

#define GL(src, dst)                                                        \
  __builtin_amdgcn_global_load_lds(                                         \
      (__attribute__((address_space(1))) void*)(src),                       \
      (__attribute__((address_space(3))) void*)(dst), 16, 0, 0)
#define STAGE_TILE(base, t)                                                 \
  {                                                                         \
    size_t ko = (size_t)(t) * 128;                                          \
    GL(sA0 + ko, (base) + p0);  GL(sA0b + ko, (base) + p1);                 \
    GL(sA1 + ko, (base) + 16384 + p0);  GL(sA1b + ko, (base) + 16384 + p1); \
    GL(sB0 + ko, (base) + 32768 + p0);  GL(sB0b + ko, (base) + 32768 + p1); \
    GL(sB1 + ko, (base) + 49152 + p0);  GL(sB1b + ko, (base) + 49152 + p1); \
  }

  int l15 = lane & 15, l4 = lane >> 4;
  int sx = (l15 & 7) << 4;
  int aoff0 = wm * 16384 + l15 * 128 + ((l4 * 16) ^ sx);
  int aoff1 = wm * 16384 + l15 * 128 + ((64 + l4 * 16) ^ sx);
  int brl = (wn & 1) * 64 + l15;
  int boff0 = 32768 + (wn >> 1) * 16384 + brl * 128 + ((l4 * 16) ^ sx);
  int boff1 = 32768 + (wn >> 1) * 16384 + brl * 128 + ((64 + l4 * 16) ^ sx);

  f32x4 acc[8][4] = {};

  STAGE_TILE(lds, 0);
  STAGE_TILE(lds + 65536, 1);
  asm volatile("s_waitcnt vmcnt(8)" ::: "memory");
  __builtin_amdgcn_sched_barrier(0);
  __builtin_amdgcn_s_barrier();
  __builtin_amdgcn_sched_barrier(0);

  for (int t = 0; t < NT; ++t) {
    char* buf = lds + (t & 1) * 65536;
    const char* a0 = buf + aoff0;
    const char* a1 = buf + aoff1;
    const char* b0 = buf + boff0;
    const char* b1 = buf + boff1;
    bf16x8 afA[4][2], afB[4][2], bfr[4][2];
#pragma unroll
    for (int ni = 0; ni < 4; ni++) {
      bfr[ni][0] = *(const bf16x8*)(b0 + ni * 2048);
      bfr[ni][1] = *(const bf16x8*)(b1 + ni * 2048);
    }
#pragma unroll
    for (int mi = 0; mi < 4; mi++) {
      afA[mi][0] = *(const bf16x8*)(a0 + mi * 2048);
      afA[mi][1] = *(const bf16x8*)(a1 + mi * 2048);
    }
#pragma unroll
    for (int mi = 0; mi < 4; mi++) {
      afB[mi][0] = *(const bf16x8*)(a0 + 8192 + mi * 2048);
      afB[mi][1] = *(const bf16x8*)(a1 + 8192 + mi * 2048);
    }
    __builtin_amdgcn_s_setprio(1);
#pragma unroll
    for (int mi = 0; mi < 4; mi++)
#pragma unroll
      for (int ni = 0; ni < 4; ni++) {
        acc[mi][ni] = __builtin_amdgcn_mfma_f32_16x16x32_bf16(afA[mi][0], bfr[ni][0], acc[mi][ni], 0, 0, 0);
        acc[mi][ni] = __builtin_amdgcn_mfma_f32_16x16x32_bf16(afA[mi][1], bfr[ni][1], acc[mi][ni], 0, 0, 0);
      }
    __builtin_amdgcn_s_setprio(0);
    asm volatile("s_waitcnt lgkmcnt(0)" ::: "memory");
    __builtin_amdgcn_sched_barrier(0);
    __builtin_amdgcn_s_barrier();
    __builtin_amdgcn_sched_barrier(0);
    if (t + 2 < NT) STAGE_TILE(buf, t + 2);
    __builtin_amdgcn_s_setprio(1);
#pragma unroll
    for (int mi = 0; mi < 4; mi++)
#pragma unroll
      for (int ni = 0; ni < 4; ni++) {
        acc[mi + 4][ni] = __builtin_amdgcn_mfma_f32_16x16x32_bf16(afB[mi][0], bfr[ni][0], acc[mi + 4][ni], 0, 0, 0);
        acc[mi + 4][ni] = __builtin_amdgcn_mfma_f32_16x16x32_bf16(afB[mi][1], bfr[ni][1], acc[mi + 4][ni], 0, 0, 0);
      }
    __builtin_amdgcn_s_setprio(0);
    if (t + 2 < NT) {
      asm volatile("s_waitcnt vmcnt(8)" ::: "memory");
    } else {
      asm volatile("s_waitcnt vmcnt(0)" ::: "memory");
    }
    __builtin_amdgcn_sched_barrier(0);
    __builtin_amdgcn_s_barrier();
    __builtin_amdgcn_sched_barrier(0);
  }

  if (mode == 0) {
    unsigned short* ob = z ? ob1 : ob0;
#pragma unroll
    for (int mi = 0; mi < 8; mi++)
#pragma unroll
      for (int ni = 0; ni < 4; ni++) {
        int col = bn + wn * 64 + ni * 16 + l15;
#pragma unroll
        for (int r = 0; r < 4; r++) {
          int m = bm + wm * 128 + mi * 16 + l4 * 4 + r;
          ob[(size_t)m * N + col] = f2bf(acc[mi][ni][r]);
        }
      }
  } else {
    const float* bias = z ? bias1 : bias0;
    float* outf = z ? of1 : of0;
#pragma unroll
    for (int mi = 0; mi < 8; mi++)
#pragma unroll
      for (int ni = 0; ni < 4; ni++) {
        int col = bn + wn * 64 + ni * 16 + l15;
        float bv = bias[col];
#pragma unroll
        for (int r = 0; r < 4; r++) {
          int m = bm + wm * 128 + mi * 16 + l4 * 4 + r;
          outf[(size_t)m * N + col] = acc[mi][ni][r] + bv;
        }
      }
  }
#undef GL
#undef STAGE_TILE
}

// ---- Flash attention, swapped-QK^T 32x32, fixed-shift softmax, MFMA l-sum,
// ---- XCD-colocated blocks (verified R13/R14: FETCH 278->49 MB) -----------
__global__ __launch_bounds__(256, 3) void attn_kernel(
    const unsigned short* __restrict__ qkvA, const unsigned short* __restrict__ qkvB,
    unsigned short* __restrict__ oA, unsigned short* __restrict__ oB) {
  __shared__ char lds[32768];  // K dbuf 2x8KB @0, Vt dbuf 2x8KB @16384
  int tid = threadIdx.x, lane = tid & 63, wid = tid >> 6;
  int hi = lane >> 5, lq = lane & 31;
  int bid = ((int)blockIdx.z * (int)gridDim.y + (int)blockIdx.y) * (int)gridDim.x +
            (int)blockIdx.x;
  int c = bid & 7, j = bid >> 3;
  int qblk = j & 15, z = (j >> 4) & 1, unit = c * 8 + (j >> 5);
  const unsigned short* Qg = z ? qkvB : qkvA;
  const unsigned short* KVg = z ? qkvA : qkvB;
  unsigned short* O = z ? oB : oA;
  int b = unit >> 4, h = unit & 15;
  int qn = qblk * 128 + wid * 32;
  const unsigned short* Qb = Qg + ((size_t)(b * 2048 + qn + lq)) * 3072 + h * 64;
  const unsigned short* Kb = KVg + (size_t)(b * 2048) * 3072 + 1024 + h * 64;
  const unsigned short* Vb = KVg + (size_t)(b * 2048) * 3072 + 2048 + h * 64;

  bf16x8 qf[4];
#pragma unroll
  for (int cc = 0; cc < 4; cc++) {
    u16x8 qr = *(const u16x8*)(Qb + cc * 16 + hi * 8);
    union { unsigned short s[8]; bf16x8 v; } u;
#pragma unroll
    for (int jj = 0; jj < 8; jj++)
      u.s[jj] = f2bf(__uint_as_float((unsigned int)qr[jj] << 16) * SM_SCALE);
    qf[cc] = u.v;
  }
  bf16x8 ones;
  {
    union { unsigned short s[8]; bf16x8 v; } u;
#pragma unroll
    for (int jj = 0; jj < 8; jj++) u.s[jj] = 0x3F80;  // bf16 1.0
    ones = u.v;
  }

  f32x16 oacc[2] = {};   // O^T: [d-half][16 regs]; col q = lane&31
  f32x16 lacc = {};      // l via ones-MFMA: every row r = l[q=lq]

  int vj = tid & 31, vd0 = (tid >> 5) * 8;
  u16x8 vr0, vr1;

#define STAGE_K(buf, t)                                                                  \
  {                                                                                      \
    char* kl_ = lds + (buf) * 8192;                                                      \
    _Pragma("unroll") for (int i_ = 0; i_ < 2; i_++) {                                   \
      int off_ = tid * 16 + i_ * 4096;                                                   \
      int row_ = off_ >> 7;                                                              \
      int col_ = off_ & 127;                                                             \
      const char* src_ = (const char*)Kb + (size_t)((t) * 64 + row_) * 6144 +            \
                         (col_ ^ ((row_ & 7) << 4));                                     \
      __builtin_amdgcn_global_load_lds(                                                  \
          (__attribute__((address_space(1))) void*)src_,                                 \
          (__attribute__((address_space(3))) void*)(kl_ + off_), 16, 0, 0);              \
    }                                                                                    \
  }
#define LOAD_V(t)                                                                        \
  {                                                                                      \
    const unsigned short* vp_ = Vb + (size_t)((t) * 64 + 2 * vj) * 3072 + vd0;           \
    vr0 = *(const u16x8*)vp_;                                                            \
    vr1 = *(const u16x8*)(vp_ + 3072);                                                   \
  }
#define WRITE_V(buf)                                                                     \
  {                                                                                      \
    char* vl_ = lds + 16384 + (buf) * 8192;                                              \
    _Pragma("unroll") for (int i_ = 0; i_ < 8; i_++) {                                   \
      unsigned int w_ = (unsigned int)vr0[i_] | ((unsigned int)vr1[i_] << 16);           \
      int d_ = vd0 + i_;                                                                 \
      int byte_ = (d_ * 128 + vj * 4) ^ ((d_ & 7) << 4);                                 \
      *(unsigned int*)(vl_ + byte_) = w_;                                                \
    }                                                                                    \
  }

  STAGE_K(0, 0);
  LOAD_V(0);
  WRITE_V(0);
  __syncthreads();

  for (int t = 0; t < 32; ++t) {
    int cur = t & 1;
    if (t + 1 < 32) { STAGE_K(cur ^ 1, t + 1); LOAD_V(t + 1); }
    const char* kl = lds + cur * 8192;
    const char* vl = lds + 16384 + cur * 8192;

#pragma unroll
    for (int hh = 0; hh < 2; hh++) {
      f32x16 st = {};
      int krow = hh * 32 + lq;
      int rbase = krow * 128 + hi * 16;
      int swz = (krow & 7) << 4;
      __builtin_amdgcn_s_setprio(1);
#pragma unroll
      for (int cc = 0; cc < 4; cc++) {
        bf16x8 kf = *(const bf16x8*)(kl + ((rbase + cc * 32) ^ swz));
        st = __builtin_amdgcn_mfma_f32_32x32x16_bf16(kf, qf[cc], st, 0, 0, 0);
      }
      __builtin_amdgcn_s_setprio(0);

#pragma unroll
      for (int i = 0; i < 16; i++) st[i] = exp2f(st[i]);

      bf16x8 pa[2];
#pragma unroll
      for (int ksl = 0; ksl < 2; ksl++) {
        unsigned int wA, wB, wC, wD;
        asm("v_cvt_pk_bf16_f32 %0, %1, %2" : "=v"(wA) : "v"(st[8 * ksl + 0]), "v"(st[8 * ksl + 1]));
        asm("v_cvt_pk_bf16_f32 %0, %1, %2" : "=v"(wC) : "v"(st[8 * ksl + 2]), "v"(st[8 * ksl + 3]));
        asm("v_cvt_pk_bf16_f32 %0, %1, %2" : "=v"(wB) : "v"(st[8 * ksl + 4]), "v"(st[8 * ksl + 5]));
        asm("v_cvt_pk_bf16_f32 %0, %1, %2" : "=v"(wD) : "v"(st[8 * ksl + 6]), "v"(st[8 * ksl + 7]));
        asm("v_permlane32_swap_b32 %0, %1" : "+v"(wA), "+v"(wB));
        asm("v_permlane32_swap_b32 %0, %1" : "+v"(wC), "+v"(wD));
        union { unsigned int w[4]; bf16x8 v; } u;
        u.w[0] = wA; u.w[1] = wC; u.w[2] = wB; u.w[3] = wD;
        pa[ksl] = u.v;
      }

      lacc = __builtin_amdgcn_mfma_f32_32x32x16_bf16(ones, pa[0], lacc, 0, 0, 0);
      lacc = __builtin_amdgcn_mfma_f32_32x32x16_bf16(ones, pa[1], lacc, 0, 0, 0);

      __builtin_amdgcn_s_setprio(1);
#pragma unroll
      for (int dh = 0; dh < 2; dh++) {
        int drow = dh * 32 + lq;
        int rb2 = drow * 128 + hi * 16;
        int sw2 = (drow & 7) << 4;
#pragma unroll
        for (int k2 = 0; k2 < 2; k2++) {
          bf16x8 vf = *(const bf16x8*)(vl + ((rb2 + (hh * 2 + k2) * 32) ^ sw2));
          oacc[dh] = __builtin_amdgcn_mfma_f32_32x32x16_bf16(vf, pa[k2], oacc[dh], 0, 0, 0);
        }
      }
      __builtin_amdgcn_s_setprio(0);
    }

    if (t + 1 < 32) WRITE_V(cur ^ 1);
    __syncthreads();
  }

  // epilogue: O^T regs -> LDS (swizzled) -> coalesced global stores
  float inv = 1.0f / lacc[0];
  char* ol = lds + wid * 4096;
#pragma unroll
  for (int dh = 0; dh < 2; dh++)
#pragma unroll
    for (int i = 0; i < 8; i++) {
      float a0 = oacc[dh][2 * i] * inv, a1 = oacc[dh][2 * i + 1] * inv;
      unsigned int w;
      asm("v_cvt_pk_bf16_f32 %0, %1, %2" : "=v"(w) : "v"(a0), "v"(a1));
      int r2 = 2 * i;
      int d = dh * 32 + (r2 & 3) + 8 * (r2 >> 2) + 4 * hi;
      int byte = (lq * 128 + d * 2) ^ ((lq & 7) << 4);
      *(unsigned int*)(ol + byte) = w;
    }
  __syncthreads();
#pragma unroll
  for (int i2 = 0; i2 < 4; i2++) {
    int qr = i2 * 8 + (lane >> 3), s = lane & 7;
    int byte = (qr * 128 + s * 16) ^ ((qr & 7) << 4);
    uint4 w4 = *(const uint4*)(ol + byte);
    size_t row = (size_t)b * 2048 + qn + qr;
    *(uint4*)((char*)O + row * 2048 + h * 128 + s * 16) = w4;
  }
#undef STAGE_K
#undef LOAD_V
#undef WRITE_V
}

extern "C" void kernel_launch(void* const* d_in, const int* in_sizes, int n_in,
                              void* d_out, int out_size, void* d_ws, size_t ws_size,
                              hipStream_t stream) {
  const float* x1 = (const float*)d_in[0];
  const float* x2 = (const float*)d_in[1];
  const float* ln1_g = (const float*)d_in[2];
  const float* ln1_b = (const float*)d_in[3];
  const float* ln2_g = (const float*)d_in[4];
  const float* ln2_b = (const float*)d_in[5];
  const float* w_qkv1 = (const float*)d_in[6];
  const float* w_qkv2 = (const float*)d_in[7];
  const float* w_out1 = (const float*)d_in[8];
  const float* b_out1 = (const float*)d_in[9];
  const float* w_out2 = (const float*)d_in[10];
  const float* b_out2 = (const float*)d_in[11];

  char* ws = (char*)d_ws;
  size_t off = 0;
  auto alloc = [&](size_t bytes) {
    char* p = ws + off;
    off += (bytes + 255) & ~(size_t)255;
    return p;
  };
  const size_t SZ16 = (size_t)8192 * 1024 * 2;   // 16.78 MB
  const size_t SZ48 = (size_t)8192 * 3072 * 2;   // 50.33 MB
  unsigned short* x1n = (unsigned short*)alloc(SZ16);
  unsigned short* x2n = (unsigned short*)alloc(SZ16);
  unsigned short* wq1T = (unsigned short*)alloc((size_t)3072 * 1024 * 2);
  unsigned short* wq2T = (unsigned short*)alloc((size_t)3072 * 1024 * 2);
  unsigned short* wo1T = (unsigned short*)alloc((size_t)1024 * 1024 * 2);
  unsigned short* wo2T = (unsigned short*)alloc((size_t)1024 * 1024 * 2);
  unsigned short* qkv1 = (unsigned short*)alloc(SZ48);
  unsigned short* qkv2 = (unsigned short*)alloc(SZ48);
  unsigned short* at1 = x1n;  // overlay: x1n dead after QKV gemm
  unsigned short* at2 = x2n;  // overlay: x2n dead after QKV gemm

  ln_kernel<<<dim3(8192, 2), dim3(256), 0, stream>>>(x1, x2, ln1_g, ln1_b,
                                                     ln2_g, ln2_b, x1n, x2n);
  transpose_w<<<dim3(128, 32, 2), dim3(256), 0, stream>>>(
      w_qkv1, w_qkv2, wq1T, wq2T, w_out1, w_out2, wo1T, wo2T);
  gemm256<<<dim3(12, 32, 2), dim3(512), 0, stream>>>(
      x1n, x2n, wq1T, wq2T, 8192, 3072, 1024, 0,
      qkv1, qkv2, nullptr, nullptr, nullptr, nullptr);
  attn_kernel<<<dim3(16, 64, 2), dim3(256), 0, stream>>>(qkv1, qkv2, at1, at2);
  gemm256<<<dim3(4, 32, 2), dim3(512), 0, stream>>>(
      at1, at2, wo1T, wo2T, 8192, 1024, 1024, 1,
      nullptr, nullptr, b_out1, b_out2,
      (float*)d_out, (float*)d_out + (size_t)8192 * 1024);
}

// Round 17
// 362.086 us; speedup vs baseline: 1.3331x; 1.0191x over previous
//
#include <hip/hip_runtime.h>

typedef __bf16 bf16x8 __attribute__((ext_vector_type(8)));
typedef float f32x4 __attribute__((ext_vector_type(4)));
typedef float f32x16 __attribute__((ext_vector_type(16)));
typedef unsigned short u16x8 __attribute__((ext_vector_type(8)));

#define SM_SCALE 0.180336880111120419f  /* 0.125 * log2(e) */

__device__ __forceinline__ unsigned short f2bf(float f) {
  unsigned int u = __float_as_uint(f);
  u += 0x7fff + ((u >> 16) & 1);   // round-to-nearest-even
  return (unsigned short)(u >> 16);
}

// -------- LayerNorm (z-merged pair): fp32 in -> bf16 normalized out -------
__global__ __launch_bounds__(256) void ln_kernel(
    const float* __restrict__ x1, const float* __restrict__ x2,
    const float* __restrict__ g1, const float* __restrict__ b1,
    const float* __restrict__ g2, const float* __restrict__ b2,
    unsigned short* __restrict__ o1, unsigned short* __restrict__ o2) {
  int z = blockIdx.y;
  const float* x = z ? x2 : x1;
  const float* g = z ? g2 : g1;
  const float* b = z ? b2 : b1;
  unsigned short* out = z ? o2 : o1;
  int row = blockIdx.x;
  int tid = threadIdx.x;
  const float4 v = ((const float4*)(x + (size_t)row * 1024))[tid];
  float s1 = v.x + v.y + v.z + v.w;
  float s2 = v.x * v.x + v.y * v.y + v.z * v.z + v.w * v.w;
  for (int o = 32; o >= 1; o >>= 1) { s1 += __shfl_xor(s1, o); s2 += __shfl_xor(s2, o); }
  __shared__ float red[2][4];
  int wid = tid >> 6, lane = tid & 63;
  if (lane == 0) { red[0][wid] = s1; red[1][wid] = s2; }
  __syncthreads();
  s1 = red[0][0] + red[0][1] + red[0][2] + red[0][3];
  s2 = red[1][0] + red[1][1] + red[1][2] + red[1][3];
  float mu = s1 * (1.0f / 1024.0f);
  float var = s2 * (1.0f / 1024.0f) - mu * mu;
  float rstd = rsqrtf(var + 1e-5f);
  int c0 = tid * 4;
  ushort4 o;
  o.x = f2bf((v.x - mu) * rstd * g[c0 + 0] + b[c0 + 0]);
  o.y = f2bf((v.y - mu) * rstd * g[c0 + 1] + b[c0 + 1]);
  o.z = f2bf((v.z - mu) * rstd * g[c0 + 2] + b[c0 + 2]);
  o.w = f2bf((v.w - mu) * rstd * g[c0 + 3] + b[c0 + 3]);
  ((ushort4*)(out + (size_t)row * 1024))[tid] = o;
}

// -- Weight transpose + cast, all four weights in ONE launch ----------------
__global__ __launch_bounds__(256) void transpose_w(
    const float* __restrict__ q0, const float* __restrict__ q1,
    unsigned short* __restrict__ qo0, unsigned short* __restrict__ qo1,
    const float* __restrict__ w0, const float* __restrict__ w1,
    unsigned short* __restrict__ wo0, unsigned short* __restrict__ wo1) {
  __shared__ float t[32][33];
  int bx = blockIdx.x;
  const float* in;
  unsigned short* out;
  int Nn, n0;
  if (bx < 96) {
    in = blockIdx.z ? q1 : q0;
    out = blockIdx.z ? qo1 : qo0;
    Nn = 3072; n0 = bx * 32;
  } else {
    in = blockIdx.z ? w1 : w0;
    out = blockIdx.z ? wo1 : wo0;
    Nn = 1024; n0 = (bx - 96) * 32;
  }
  const int K = 1024;
  int tid = threadIdx.x;
  int tx = tid & 31, ty = tid >> 5;
  int k0 = blockIdx.y * 32;
#pragma unroll
  for (int i = 0; i < 4; i++) {
    int r = ty + i * 8;
    t[r][tx] = in[(size_t)(k0 + r) * Nn + n0 + tx];
  }
  __syncthreads();
#pragma unroll
  for (int i = 0; i < 4; i++) {
    int r = ty + i * 8;
    out[(size_t)(n0 + r) * K + k0 + tx] = f2bf(t[tx][r]);
  }
}

// ---- 256x256 8-wave bf16 GEMM, z-merged pair with XCD-half partition -----
// mode 0 (QKV): cols<2048 -> qk[8192][2048] row-major; cols>=2048 (V) ->
//   Vt[unit][d][kpos] TRANSPOSED via packed ushort4 (4 contiguous kpos).
// mode 1: fp32 + bias -> outf [M][N]
__global__ __launch_bounds__(512, 2) void gemm256(
    const unsigned short* __restrict__ A0, const unsigned short* __restrict__ A1,
    const unsigned short* __restrict__ BT0, const unsigned short* __restrict__ BT1,
    int M, int N, int K, int mode,
    unsigned short* __restrict__ ob0, unsigned short* __restrict__ ob1,
    unsigned short* __restrict__ vt0, unsigned short* __restrict__ vt1,
    const float* __restrict__ bias0, const float* __restrict__ bias1,
    float* __restrict__ of0, float* __restrict__ of1) {
  __shared__ char lds[131072];
  const int tid = threadIdx.x;
  const int lane = tid & 63, wid = tid >> 6;
  const int wm = wid >> 2, wn = wid & 3;
  int gx = gridDim.x, gy = gridDim.y;
  int hb = ((int)blockIdx.z * gy + (int)blockIdx.y) * gx + (int)blockIdx.x;
  int c = hb & 7, j = hb >> 3;
  int z = c >> 2;
  int chunk = gy >> 2;
  int by = (c & 3) * chunk + (j % chunk);
  int bx = j / chunk;
  int bm = by * 256, bn = bx * 256;
  const unsigned short* A = z ? A1 : A0;
  const unsigned short* BT = z ? BT1 : BT0;
  const int NT = K >> 6;
  const size_t K2 = (size_t)K * 2;

  int p0 = tid * 16, p1 = 8192 + tid * 16;
  int r0 = p0 >> 7, r1 = p1 >> 7;
  int c0 = (p0 & 127) ^ ((r0 & 7) << 4);
  int c1 = (p1 & 127) ^ ((r1 & 7) << 4);
  const char* sA0 = (const char*)A + (size_t)(bm + r0) * K2 + c0;
  const char* sA0b = (const char*)A + (size_t)(bm + r1) * K2 + c1;
  const char* sA1 = (const char*)A + (size_t)(bm + 128 + r0) * K2 + c0;
  const char* sA1b = (const char*)A + (size_t)(bm + 128 + r1) * K2 + c1;
  const char* sB0 = (const char*)BT + (size_t)(bn + r0) * K2 + c0;
  const char* sB0b = (const char*)BT + (size_t)(bn + r1) * K2 + c1;
  const char* sB1 = (const char*)BT + (size_t)(bn + 128 + r0) * K2 + c0;
  const char* sB1b = (const char*)BT + (size_t)(bn + 128 + r1) * K2 + c1;

#define GL(src, dst)                                                        \
  __builtin_amdgcn_global_load_lds(                                         \
      (__attribute__((address_space(1))) void*)(src),                       \
      (__attribute__((address_space(3))) void*)(dst), 16, 0, 0)
#define STAGE_TILE(base, t)                                                 \
  {                                                                         \
    size_t ko = (size_t)(t) * 128;                                          \
    GL(sA0 + ko, (base) + p0);  GL(sA0b + ko, (base) + p1);                 \
    GL(sA1 + ko, (base) + 16384 + p0);  GL(sA1b + ko, (base) + 16384 + p1); \
    GL(sB0 + ko, (base) + 32768 + p0);  GL(sB0b + ko, (base) + 32768 + p1); \
    GL(sB1 + ko, (base) + 49152 + p0);  GL(sB1b + ko, (base) + 49152 + p1); \
  }

  int l15 = lane & 15, l4 = lane >> 4;
  int sx = (l15 & 7) << 4;
  int aoff0 = wm * 16384 + l15 * 128 + ((l4 * 16) ^ sx);
  int aoff1 = wm * 16384 + l15 * 128 + ((64 + l4 * 16) ^ sx);
  int brl = (wn & 1) * 64 + l15;
  int boff0 = 32768 + (wn >> 1) * 16384 + brl * 128 + ((l4 * 16) ^ sx);
  int boff1 = 32768 + (wn >> 1) * 16384 + brl * 128 + ((64 + l4 * 16) ^ sx);

  f32x4 acc[8][4] = {};

  STAGE_TILE(lds, 0);
  STAGE_TILE(lds + 65536, 1);
  asm volatile("s_waitcnt vmcnt(8)" ::: "memory");
  __builtin_amdgcn_sched_barrier(0);
  __builtin_amdgcn_s_barrier();
  __builtin_amdgcn_sched_barrier(0);

  for (int t = 0; t < NT; ++t) {
    char* buf = lds + (t & 1) * 65536;
    const char* a0 = buf + aoff0;
    const char* a1 = buf + aoff1;
    const char* b0 = buf + boff0;
    const char* b1 = buf + boff1;
    bf16x8 afA[4][2], afB[4][2], bfr[4][2];
#pragma unroll
    for (int ni = 0; ni < 4; ni++) {
      bfr[ni][0] = *(const bf16x8*)(b0 + ni * 2048);
      bfr[ni][1] = *(const bf16x8*)(b1 + ni * 2048);
    }
#pragma unroll
    for (int mi = 0; mi < 4; mi++) {
      afA[mi][0] = *(const bf16x8*)(a0 + mi * 2048);
      afA[mi][1] = *(const bf16x8*)(a1 + mi * 2048);
    }
#pragma unroll
    for (int mi = 0; mi < 4; mi++) {
      afB[mi][0] = *(const bf16x8*)(a0 + 8192 + mi * 2048);
      afB[mi][1] = *(const bf16x8*)(a1 + 8192 + mi * 2048);
    }
    __builtin_amdgcn_s_setprio(1);
#pragma unroll
    for (int mi = 0; mi < 4; mi++)
#pragma unroll
      for (int ni = 0; ni < 4; ni++) {
        acc[mi][ni] = __builtin_amdgcn_mfma_f32_16x16x32_bf16(afA[mi][0], bfr[ni][0], acc[mi][ni], 0, 0, 0);
        acc[mi][ni] = __builtin_amdgcn_mfma_f32_16x16x32_bf16(afA[mi][1], bfr[ni][1], acc[mi][ni], 0, 0, 0);
      }
    __builtin_amdgcn_s_setprio(0);
    asm volatile("s_waitcnt lgkmcnt(0)" ::: "memory");
    __builtin_amdgcn_sched_barrier(0);
    __builtin_amdgcn_s_barrier();
    __builtin_amdgcn_sched_barrier(0);
    if (t + 2 < NT) STAGE_TILE(buf, t + 2);
    __builtin_amdgcn_s_setprio(1);
#pragma unroll
    for (int mi = 0; mi < 4; mi++)
#pragma unroll
      for (int ni = 0; ni < 4; ni++) {
        acc[mi + 4][ni] = __builtin_amdgcn_mfma_f32_16x16x32_bf16(afB[mi][0], bfr[ni][0], acc[mi + 4][ni], 0, 0, 0);
        acc[mi + 4][ni] = __builtin_amdgcn_mfma_f32_16x16x32_bf16(afB[mi][1], bfr[ni][1], acc[mi + 4][ni], 0, 0, 0);
      }
    __builtin_amdgcn_s_setprio(0);
    if (t + 2 < NT) {
      asm volatile("s_waitcnt vmcnt(8)" ::: "memory");
    } else {
      asm volatile("s_waitcnt vmcnt(0)" ::: "memory");
    }
    __builtin_amdgcn_sched_barrier(0);
    __builtin_amdgcn_s_barrier();
    __builtin_amdgcn_sched_barrier(0);
  }

  if (mode == 0) {
    if (bn >= 2048) {
      // V block: write transposed into Vt[unit][d][kpos], 4 kpos per store
      unsigned short* vt = z ? vt1 : vt0;
      int b_ = bm >> 11, mb = bm & 2047;
#pragma unroll
      for (int mi = 0; mi < 8; mi++)
#pragma unroll
        for (int ni = 0; ni < 4; ni++) {
          int hn = bn - 2048 + wn * 64 + ni * 16 + l15;   // 0..1023
          size_t vrow = (size_t)(b_ * 16 + (hn >> 6)) * 64 + (hn & 63);
          int kp = mb + wm * 128 + mi * 16 + l4 * 4;
          ushort4 pk;
          pk.x = f2bf(acc[mi][ni][0]);
          pk.y = f2bf(acc[mi][ni][1]);
          pk.z = f2bf(acc[mi][ni][2]);
          pk.w = f2bf(acc[mi][ni][3]);
          *(ushort4*)(vt + vrow * 2048 + kp) = pk;
        }
    } else {
      unsigned short* ob = z ? ob1 : ob0;   // qk [8192][2048]
#pragma unroll
      for (int mi = 0; mi < 8; mi++)
#pragma unroll
        for (int ni = 0; ni < 4; ni++) {
          int col = bn + wn * 64 + ni * 16 + l15;
#pragma unroll
          for (int r = 0; r < 4; r++) {
            int m = bm + wm * 128 + mi * 16 + l4 * 4 + r;
            ob[(size_t)m * 2048 + col] = f2bf(acc[mi][ni][r]);
          }
        }
    }
  } else {
    const float* bias = z ? bias1 : bias0;
    float* outf = z ? of1 : of0;
#pragma unroll
    for (int mi = 0; mi < 8; mi++)
#pragma unroll
      for (int ni = 0; ni < 4; ni++) {
        int col = bn + wn * 64 + ni * 16 + l15;
        float bv = bias[col];
#pragma unroll
        for (int r = 0; r < 4; r++) {
          int m = bm + wm * 128 + mi * 16 + l4 * 4 + r;
          outf[(size_t)m * N + col] = acc[mi][ni][r] + bv;
        }
      }
  }
#undef GL
#undef STAGE_TILE
}

// ---- Flash attention: swapped-QK^T 32x32, fixed-shift softmax, MFMA l-sum,
// ---- XCD-colocated; K from qk[.][2048], V^T pre-transposed in Vt ->
// ---- both staged via global_load_lds (no in-kernel transpose) ------------
__global__ __launch_bounds__(256, 3) void attn_kernel(
    const unsigned short* __restrict__ qkA, const unsigned short* __restrict__ qkB,
    const unsigned short* __restrict__ vtA, const unsigned short* __restrict__ vtB,
    unsigned short* __restrict__ oA, unsigned short* __restrict__ oB) {
  __shared__ char lds[32768];  // K dbuf 2x8KB @0, Vt dbuf 2x8KB @16384
  int tid = threadIdx.x, lane = tid & 63, wid = tid >> 6;
  int hi = lane >> 5, lq = lane & 31;
  int bid = ((int)blockIdx.z * (int)gridDim.y + (int)blockIdx.y) * (int)gridDim.x +
            (int)blockIdx.x;
  int c = bid & 7, j = bid >> 3;
  int qblk = j & 15, z = (j >> 4) & 1, unit = c * 8 + (j >> 5);
  const unsigned short* Qg = z ? qkB : qkA;
  const unsigned short* Kg = z ? qkA : qkB;
  const unsigned short* Vtg = z ? vtA : vtB;
  unsigned short* O = z ? oB : oA;
  int b = unit >> 4, h = unit & 15;
  int qn = qblk * 128 + wid * 32;
  const unsigned short* Qb = Qg + ((size_t)(b * 2048 + qn + lq)) * 2048 + h * 64;
  const char* Kb = (const char*)(Kg + (size_t)(b * 2048) * 2048 + 1024 + h * 64);
  const char* VtU = (const char*)(Vtg + (size_t)unit * 64 * 2048);

  bf16x8 qf[4];
#pragma unroll
  for (int cc = 0; cc < 4; cc++) {
    u16x8 qr = *(const u16x8*)(Qb + cc * 16 + hi * 8);
    union { unsigned short s[8]; bf16x8 v; } u;
#pragma unroll
    for (int jj = 0; jj < 8; jj++)
      u.s[jj] = f2bf(__uint_as_float((unsigned int)qr[jj] << 16) * SM_SCALE);
    qf[cc] = u.v;
  }
  bf16x8 ones;
  {
    union { unsigned short s[8]; bf16x8 v; } u;
#pragma unroll
    for (int jj = 0; jj < 8; jj++) u.s[jj] = 0x3F80;  // bf16 1.0
    ones = u.v;
  }

  f32x16 oacc[2] = {};   // O^T: [d-half][16 regs]; col q = lane&31
  f32x16 lacc = {};      // l via ones-MFMA: every row r = l[q=lq]

#define STAGE_K(buf, t)                                                                  \
  {                                                                                      \
    char* kl_ = lds + (buf) * 8192;                                                      \
    _Pragma("unroll") for (int i_ = 0; i_ < 2; i_++) {                                   \
      int off_ = tid * 16 + i_ * 4096;                                                   \
      int row_ = off_ >> 7;                                                              \
      int col_ = off_ & 127;                                                             \
      const char* src_ = Kb + (size_t)((t) * 64 + row_) * 4096 +                         \
                         (col_ ^ ((row_ & 7) << 4));                                     \
      __builtin_amdgcn_global_load_lds(                                                  \
          (__attribute__((address_space(1))) void*)src_,                                 \
          (__attribute__((address_space(3))) void*)(kl_ + off_), 16, 0, 0);              \
    }                                                                                    \
  }
#define STAGE_V(buf, t)                                                                  \
  {                                                                                      \
    char* vl_ = lds + 16384 + (buf) * 8192;                                              \
    _Pragma("unroll") for (int i_ = 0; i_ < 2; i_++) {                                   \
      int off_ = tid * 16 + i_ * 4096;                                                   \
      int row_ = off_ >> 7;                                                              \
      int col_ = off_ & 127;                                                             \
      const char* src_ = VtU + (size_t)row_ * 4096 + (t) * 128 +                         \
                         (col_ ^ ((row_ & 7) << 4));                                     \
      __builtin_amdgcn_global_load_lds(                                                  \
          (__attribute__((address_space(1))) void*)src_,                                 \
          (__attribute__((address_space(3))) void*)(vl_ + off_), 16, 0, 0);              \
    }                                                                                    \
  }

  STAGE_K(0, 0);
  STAGE_V(0, 0);
  __syncthreads();

  for (int t = 0; t < 32; ++t) {
    int cur = t & 1;
    if (t + 1 < 32) { STAGE_K(cur ^ 1, t + 1); STAGE_V(cur ^ 1, t + 1); }
    const char* kl = lds + cur * 8192;
    const char* vl = lds + 16384 + cur * 8192;

#pragma unroll
    for (int hh = 0; hh < 2; hh++) {
      f32x16 st = {};
      int krow = hh * 32 + lq;
      int rbase = krow * 128 + hi * 16;
      int swz = (krow & 7) << 4;
      __builtin_amdgcn_s_setprio(1);
#pragma unroll
      for (int cc = 0; cc < 4; cc++) {
        bf16x8 kf = *(const bf16x8*)(kl + ((rbase + cc * 32) ^ swz));
        st = __builtin_amdgcn_mfma_f32_32x32x16_bf16(kf, qf[cc], st, 0, 0, 0);
      }
      __builtin_amdgcn_s_setprio(0);

#pragma unroll
      for (int i = 0; i < 16; i++) st[i] = exp2f(st[i]);

      bf16x8 pa[2];
#pragma unroll
      for (int ksl = 0; ksl < 2; ksl++) {
        unsigned int wA, wB, wC, wD;
        asm("v_cvt_pk_bf16_f32 %0, %1, %2" : "=v"(wA) : "v"(st[8 * ksl + 0]), "v"(st[8 * ksl + 1]));
        asm("v_cvt_pk_bf16_f32 %0, %1, %2" : "=v"(wC) : "v"(st[8 * ksl + 2]), "v"(st[8 * ksl + 3]));
        asm("v_cvt_pk_bf16_f32 %0, %1, %2" : "=v"(wB) : "v"(st[8 * ksl + 4]), "v"(st[8 * ksl + 5]));
        asm("v_cvt_pk_bf16_f32 %0, %1, %2" : "=v"(wD) : "v"(st[8 * ksl + 6]), "v"(st[8 * ksl + 7]));
        asm("v_permlane32_swap_b32 %0, %1" : "+v"(wA), "+v"(wB));
        asm("v_permlane32_swap_b32 %0, %1" : "+v"(wC), "+v"(wD));
        union { unsigned int w[4]; bf16x8 v; } u;
        u.w[0] = wA; u.w[1] = wC; u.w[2] = wB; u.w[3] = wD;
        pa[ksl] = u.v;
      }

      lacc = __builtin_amdgcn_mfma_f32_32x32x16_bf16(ones, pa[0], lacc, 0, 0, 0);
      lacc = __builtin_amdgcn_mfma_f32_32x32x16_bf16(ones, pa[1], lacc, 0, 0, 0);

      __builtin_amdgcn_s_setprio(1);
#pragma unroll
      for (int dh = 0; dh < 2; dh++) {
        int drow = dh * 32 + lq;
        int rb2 = drow * 128 + hi * 16;
        int sw2 = (drow & 7) << 4;
#pragma unroll
        for (int k2 = 0; k2 < 2; k2++) {
          bf16x8 vf = *(const bf16x8*)(vl + ((rb2 + (hh * 2 + k2) * 32) ^ sw2));
          oacc[dh] = __builtin_amdgcn_mfma_f32_32x32x16_bf16(vf, pa[k2], oacc[dh], 0, 0, 0);
        }
      }
      __builtin_amdgcn_s_setprio(0);
    }
    __syncthreads();
  }

  // epilogue: O^T regs -> LDS (swizzled) -> coalesced global stores
  float inv = 1.0f / lacc[0];
  char* ol = lds + wid * 4096;
#pragma unroll
  for (int dh = 0; dh < 2; dh++)
#pragma unroll
    for (int i = 0; i < 8; i++) {
      float a0 = oacc[dh][2 * i] * inv, a1 = oacc[dh][2 * i + 1] * inv;
      unsigned int w;
      asm("v_cvt_pk_bf16_f32 %0, %1, %2" : "=v"(w) : "v"(a0), "v"(a1));
      int r2 = 2 * i;
      int d = dh * 32 + (r2 & 3) + 8 * (r2 >> 2) + 4 * hi;
      int byte = (lq * 128 + d * 2) ^ ((lq & 7) << 4);
      *(unsigned int*)(ol + byte) = w;
    }
  __syncthreads();
#pragma unroll
  for (int i2 = 0; i2 < 4; i2++) {
    int qr = i2 * 8 + (lane >> 3), s = lane & 7;
    int byte = (qr * 128 + s * 16) ^ ((qr & 7) << 4);
    uint4 w4 = *(const uint4*)(ol + byte);
    size_t row = (size_t)b * 2048 + qn + qr;
    *(uint4*)((char*)O + row * 2048 + h * 128 + s * 16) = w4;
  }
#undef STAGE_K
#undef STAGE_V
}

extern "C" void kernel_launch(void* const* d_in, const int* in_sizes, int n_in,
                              void* d_out, int out_size, void* d_ws, size_t ws_size,
                              hipStream_t stream) {
  const float* x1 = (const float*)d_in[0];
  const float* x2 = (const float*)d_in[1];
  const float* ln1_g = (const float*)d_in[2];
  const float* ln1_b = (const float*)d_in[3];
  const float* ln2_g = (const float*)d_in[4];
  const float* ln2_b = (const float*)d_in[5];
  const float* w_qkv1 = (const float*)d_in[6];
  const float* w_qkv2 = (const float*)d_in[7];
  const float* w_out1 = (const float*)d_in[8];
  const float* b_out1 = (const float*)d_in[9];
  const float* w_out2 = (const float*)d_in[10];
  const float* b_out2 = (const float*)d_in[11];

  char* ws = (char*)d_ws;
  size_t off = 0;
  auto alloc = [&](size_t bytes) {
    char* p = ws + off;
    off += (bytes + 255) & ~(size_t)255;
    return p;
  };
  const size_t SZ16 = (size_t)8192 * 1024 * 2;   // 16.78 MB
  const size_t SZ32 = (size_t)8192 * 2048 * 2;   // 33.55 MB
  unsigned short* x1n = (unsigned short*)alloc(SZ16);
  unsigned short* x2n = (unsigned short*)alloc(SZ16);
  unsigned short* wq1T = (unsigned short*)alloc((size_t)3072 * 1024 * 2);
  unsigned short* wq2T = (unsigned short*)alloc((size_t)3072 * 1024 * 2);
  unsigned short* wo1T = (unsigned short*)alloc((size_t)1024 * 1024 * 2);
  unsigned short* wo2T = (unsigned short*)alloc((size_t)1024 * 1024 * 2);
  unsigned short* qk1 = (unsigned short*)alloc(SZ32);
  unsigned short* qk2 = (unsigned short*)alloc(SZ32);
  unsigned short* vt1 = (unsigned short*)alloc(SZ16);
  unsigned short* vt2 = (unsigned short*)alloc(SZ16);
  unsigned short* at1 = x1n;  // overlay: x1n dead after QKV gemm
  unsigned short* at2 = x2n;  // overlay: x2n dead after QKV gemm

  ln_kernel<<<dim3(8192, 2), dim3(256), 0, stream>>>(x1, x2, ln1_g, ln1_b,
                                                     ln2_g, ln2_b, x1n, x2n);
  transpose_w<<<dim3(128, 32, 2), dim3(256), 0, stream>>>(
      w_qkv1, w_qkv2, wq1T, wq2T, w_out1, w_out2, wo1T, wo2T);
  gemm256<<<dim3(12, 32, 2), dim3(512), 0, stream>>>(
      x1n, x2n, wq1T, wq2T, 8192, 3072, 1024, 0,
      qk1, qk2, vt1, vt2, nullptr, nullptr, nullptr, nullptr);
  attn_kernel<<<dim3(16, 64, 2), dim3(256), 0, stream>>>(qk1, qk2, vt1, vt2, at1, at2);
  gemm256<<<dim3(4, 32, 2), dim3(512), 0, stream>>>(
      at1, at2, wo1T, wo2T, 8192, 1024, 1024, 1,
      nullptr, nullptr, nullptr, nullptr, b_out1, b_out2,
      (float*)d_out, (float*)d_out + (size_t)8192 * 1024);
}